// Round 1
// baseline (283.438 us; speedup 1.0000x reference)
//
#include <hip/hip_runtime.h>

// Problem shape (fixed by reference setup_inputs):
//   x, target: [B=8, C=256, H=128, W=128] float32, contiguous.
//   Reduction over (B,H,W) -> per-channel moments 1..5; loss = sum of 5
//   RMSE-sum terms over the C=256 moment vectors.
#define B_DIM 8
#define C_DIM 256
#define HW    16384                 // 128*128, contiguous per (b,c)
#define NBLK  (B_DIM * C_DIM)       // 2048 blocks, one per (b,c) slab
#define N_PER_CHAN (B_DIM * HW)     // 131072 elements per channel

// ---------------------------------------------------------------------------
// Kernel 1: one pass over both tensors. Each block owns one contiguous
// 16384-float slab of x and the matching slab of target. Computes raw power
// sums v^1..v^5 for both tensors (10 accumulators), reduces within the block,
// writes 10 fp32 partials to ws: partial[s * NBLK + bid].
// ---------------------------------------------------------------------------
__global__ __launch_bounds__(256) void pow_sums_kernel(
    const float* __restrict__ x,
    const float* __restrict__ t,
    float* __restrict__ partial)
{
    const int bid = blockIdx.x;
    const int tid = threadIdx.x;

    const float4* __restrict__ xv = (const float4*)(x + (size_t)bid * HW);
    const float4* __restrict__ tv = (const float4*)(t + (size_t)bid * HW);

    float s[10];
#pragma unroll
    for (int k = 0; k < 10; ++k) s[k] = 0.0f;

    // v, v2=v*v, v3=v2*v; fma-friendly accumulation of powers 1..5.
#define ACC1(v, o)                        \
    {                                     \
        float _v  = (v);                  \
        float _v2 = _v * _v;              \
        float _v3 = _v2 * _v;             \
        s[(o) + 0] += _v;                 \
        s[(o) + 1] += _v2;                \
        s[(o) + 2] += _v3;                \
        s[(o) + 3] += _v2 * _v2;          \
        s[(o) + 4] += _v3 * _v2;          \
    }

#pragma unroll 4
    for (int i = tid; i < HW / 4; i += 256) {
        float4 a = xv[i];
        float4 b = tv[i];
        ACC1(a.x, 0) ACC1(a.y, 0) ACC1(a.z, 0) ACC1(a.w, 0)
        ACC1(b.x, 5) ACC1(b.y, 5) ACC1(b.z, 5) ACC1(b.w, 5)
    }
#undef ACC1

    // Wave-level butterfly reduce (wave = 64 lanes on gfx950).
#pragma unroll
    for (int off = 32; off > 0; off >>= 1) {
#pragma unroll
        for (int k = 0; k < 10; ++k) s[k] += __shfl_down(s[k], off, 64);
    }

    __shared__ float wsum[4][10];
    const int wave = tid >> 6;
    const int lane = tid & 63;
    if (lane == 0) {
#pragma unroll
        for (int k = 0; k < 10; ++k) wsum[wave][k] = s[k];
    }
    __syncthreads();

    if (tid < 10) {
        float v = wsum[0][tid] + wsum[1][tid] + wsum[2][tid] + wsum[3][tid];
        partial[tid * NBLK + bid] = v;
    }
}

// ---------------------------------------------------------------------------
// Kernel 2: single block, 256 threads (thread c = channel c). Combines the
// 8 per-batch partials per channel in fp64, converts raw moments to central
// moments via binomial identities, reduces the 5 squared-diff sums across
// channels, writes the scalar loss.
// ---------------------------------------------------------------------------
__global__ __launch_bounds__(256) void finalize_kernel(
    const float* __restrict__ partial,
    float* __restrict__ out)
{
    const int c = threadIdx.x;  // channel

    double S[10];
#pragma unroll
    for (int k = 0; k < 10; ++k) S[k] = 0.0;

    for (int b = 0; b < B_DIM; ++b) {
        const int bid = b * C_DIM + c;  // coalesced across threads
#pragma unroll
        for (int k = 0; k < 10; ++k) S[k] += (double)partial[k * NBLK + bid];
    }

    const double invN = 1.0 / (double)N_PER_CHAN;

    // x raw moments
    const double mux = S[0] * invN;
    const double M2x = S[1] * invN, M3x = S[2] * invN;
    const double M4x = S[3] * invN, M5x = S[4] * invN;
    // y raw moments
    const double muy = S[5] * invN;
    const double M2y = S[6] * invN, M3y = S[7] * invN;
    const double M4y = S[8] * invN, M5y = S[9] * invN;

    // Central moments via binomial expansion about the mean.
    const double mux2 = mux * mux, mux3 = mux2 * mux;
    const double c2x = M2x - mux2;
    const double c3x = M3x - 3.0 * mux * M2x + 2.0 * mux3;
    const double c4x = M4x - 4.0 * mux * M3x + 6.0 * mux2 * M2x - 3.0 * mux2 * mux2;
    const double c5x = M5x - 5.0 * mux * M4x + 10.0 * mux2 * M3x
                       - 10.0 * mux3 * M2x + 4.0 * mux3 * mux2;

    const double muy2 = muy * muy, muy3 = muy2 * muy;
    const double c2y = M2y - muy2;
    const double c3y = M3y - 3.0 * muy * M2y + 2.0 * muy3;
    const double c4y = M4y - 4.0 * muy * M3y + 6.0 * muy2 * M2y - 3.0 * muy2 * muy2;
    const double c5y = M5y - 5.0 * muy * M4y + 10.0 * muy2 * M3y
                       - 10.0 * muy3 * M2y + 4.0 * muy3 * muy2;

    const double d1 = mux - muy;
    const double d2 = c2x - c2y;
    const double d3 = c3x - c3y;
    const double d4 = c4x - c4y;
    const double d5 = c5x - c5y;

    __shared__ double red[5][C_DIM];
    red[0][c] = d1 * d1;
    red[1][c] = d2 * d2;
    red[2][c] = d3 * d3;
    red[3][c] = d4 * d4;
    red[4][c] = d5 * d5;
    __syncthreads();

    for (int st = 128; st > 0; st >>= 1) {
        if (c < st) {
#pragma unroll
            for (int k = 0; k < 5; ++k) red[k][c] += red[k][c + st];
        }
        __syncthreads();
    }

    if (c == 0) {
        out[0] = (float)(sqrt(red[0][0]) + sqrt(red[1][0]) + sqrt(red[2][0])
                         + sqrt(red[3][0]) + sqrt(red[4][0]));
    }
}

extern "C" void kernel_launch(void* const* d_in, const int* in_sizes, int n_in,
                              void* d_out, int out_size, void* d_ws, size_t ws_size,
                              hipStream_t stream) {
    const float* x = (const float*)d_in[0];       // x
    const float* t = (const float*)d_in[1];       // target
    float* out = (float*)d_out;                   // scalar fp32 loss
    float* partial = (float*)d_ws;                // 10 * 2048 floats = 80 KB

    pow_sums_kernel<<<NBLK, 256, 0, stream>>>(x, t, partial);
    finalize_kernel<<<1, 256, 0, stream>>>(partial, out);
}

// Round 2
// 279.721 us; speedup vs baseline: 1.0133x; 1.0133x over previous
//
#include <hip/hip_runtime.h>

// Problem shape (fixed by reference setup_inputs):
//   x, target: [B=8, C=256, H=128, W=128] float32, contiguous.
//   Reduction over (B,H,W) -> per-channel moments 1..5; loss = sum of 5
//   RMSE-sum terms over the C=256 moment vectors.
#define B_DIM 8
#define C_DIM 256
#define HW    16384                 // 128*128, contiguous per (b,c)
#define NBLK  (B_DIM * C_DIM)       // 2048 blocks, one per (b,c) slab
#define N_PER_CHAN (B_DIM * HW)     // 131072 elements per channel

// ---------------------------------------------------------------------------
// Kernel 1: one pass over both tensors. Each block owns one contiguous
// 16384-float slab of x and the matching slab of target.
//
// R1 lesson: 2 float4 loads in flight per wave -> latency-bound at 2.55 TB/s
// effective (VALUBusy 11%, hbm 16% peak). Fix: batch 8 independent float4
// loads (128 B/lane) before any use, so each wave keeps 8 KB outstanding.
// ---------------------------------------------------------------------------
__global__ __launch_bounds__(256) void pow_sums_kernel(
    const float* __restrict__ x,
    const float* __restrict__ t,
    float* __restrict__ partial)
{
    const int bid = blockIdx.x;
    const int tid = threadIdx.x;

    const float4* __restrict__ xv = (const float4*)(x + (size_t)bid * HW);
    const float4* __restrict__ tv = (const float4*)(t + (size_t)bid * HW);

    float s[10];
#pragma unroll
    for (int k = 0; k < 10; ++k) s[k] = 0.0f;

    // Powers 1..5 of one element accumulated into s[o..o+4].
#define ACC1(v, o)                        \
    {                                     \
        float _v  = (v);                  \
        float _v2 = _v * _v;              \
        float _v3 = _v2 * _v;             \
        s[(o) + 0] += _v;                 \
        s[(o) + 1] += _v2;                \
        s[(o) + 2] += _v3;                \
        s[(o) + 3] += _v2 * _v2;          \
        s[(o) + 4] += _v3 * _v2;          \
    }
#define ACC4(f, o) ACC1((f).x, o) ACC1((f).y, o) ACC1((f).z, o) ACC1((f).w, o)

    // 16 float4/thread per tensor, consumed in 4 batches of (4x + 4t) loads.
    // All 8 loads of a batch are independent and issue before any use.
#pragma unroll
    for (int j = 0; j < 4; ++j) {
        const int base = tid + j * 1024;      // 4 * 256 threads
        float4 a0 = xv[base];
        float4 a1 = xv[base + 256];
        float4 a2 = xv[base + 512];
        float4 a3 = xv[base + 768];
        float4 b0 = tv[base];
        float4 b1 = tv[base + 256];
        float4 b2 = tv[base + 512];
        float4 b3 = tv[base + 768];
        ACC4(a0, 0) ACC4(a1, 0) ACC4(a2, 0) ACC4(a3, 0)
        ACC4(b0, 5) ACC4(b1, 5) ACC4(b2, 5) ACC4(b3, 5)
    }
#undef ACC4
#undef ACC1

    // Wave-level butterfly reduce (wave = 64 lanes on gfx950).
#pragma unroll
    for (int off = 32; off > 0; off >>= 1) {
#pragma unroll
        for (int k = 0; k < 10; ++k) s[k] += __shfl_down(s[k], off, 64);
    }

    __shared__ float wsum[4][10];
    const int wave = tid >> 6;
    const int lane = tid & 63;
    if (lane == 0) {
#pragma unroll
        for (int k = 0; k < 10; ++k) wsum[wave][k] = s[k];
    }
    __syncthreads();

    if (tid < 10) {
        float v = wsum[0][tid] + wsum[1][tid] + wsum[2][tid] + wsum[3][tid];
        partial[tid * NBLK + bid] = v;
    }
}

// ---------------------------------------------------------------------------
// Kernel 2: single block, 256 threads (thread c = channel c). Combines the
// 8 per-batch partials per channel in fp64, converts raw moments to central
// moments via binomial identities, reduces the 5 squared-diff sums across
// channels, writes the scalar loss.
// ---------------------------------------------------------------------------
__global__ __launch_bounds__(256) void finalize_kernel(
    const float* __restrict__ partial,
    float* __restrict__ out)
{
    const int c = threadIdx.x;  // channel

    double S[10];
#pragma unroll
    for (int k = 0; k < 10; ++k) S[k] = 0.0;

    for (int b = 0; b < B_DIM; ++b) {
        const int bid = b * C_DIM + c;  // coalesced across threads
#pragma unroll
        for (int k = 0; k < 10; ++k) S[k] += (double)partial[k * NBLK + bid];
    }

    const double invN = 1.0 / (double)N_PER_CHAN;

    // x raw moments
    const double mux = S[0] * invN;
    const double M2x = S[1] * invN, M3x = S[2] * invN;
    const double M4x = S[3] * invN, M5x = S[4] * invN;
    // y raw moments
    const double muy = S[5] * invN;
    const double M2y = S[6] * invN, M3y = S[7] * invN;
    const double M4y = S[8] * invN, M5y = S[9] * invN;

    // Central moments via binomial expansion about the mean.
    const double mux2 = mux * mux, mux3 = mux2 * mux;
    const double c2x = M2x - mux2;
    const double c3x = M3x - 3.0 * mux * M2x + 2.0 * mux3;
    const double c4x = M4x - 4.0 * mux * M3x + 6.0 * mux2 * M2x - 3.0 * mux2 * mux2;
    const double c5x = M5x - 5.0 * mux * M4x + 10.0 * mux2 * M3x
                       - 10.0 * mux3 * M2x + 4.0 * mux3 * mux2;

    const double muy2 = muy * muy, muy3 = muy2 * muy;
    const double c2y = M2y - muy2;
    const double c3y = M3y - 3.0 * muy * M2y + 2.0 * muy3;
    const double c4y = M4y - 4.0 * muy * M3y + 6.0 * muy2 * M2y - 3.0 * muy2 * muy2;
    const double c5y = M5y - 5.0 * muy * M4y + 10.0 * muy2 * M3y
                       - 10.0 * muy3 * M2y + 4.0 * muy3 * muy2;

    const double d1 = mux - muy;
    const double d2 = c2x - c2y;
    const double d3 = c3x - c3y;
    const double d4 = c4x - c4y;
    const double d5 = c5x - c5y;

    __shared__ double red[5][C_DIM];
    red[0][c] = d1 * d1;
    red[1][c] = d2 * d2;
    red[2][c] = d3 * d3;
    red[3][c] = d4 * d4;
    red[4][c] = d5 * d5;
    __syncthreads();

    for (int st = 128; st > 0; st >>= 1) {
        if (c < st) {
#pragma unroll
            for (int k = 0; k < 5; ++k) red[k][c] += red[k][c + st];
        }
        __syncthreads();
    }

    if (c == 0) {
        out[0] = (float)(sqrt(red[0][0]) + sqrt(red[1][0]) + sqrt(red[2][0])
                         + sqrt(red[3][0]) + sqrt(red[4][0]));
    }
}

extern "C" void kernel_launch(void* const* d_in, const int* in_sizes, int n_in,
                              void* d_out, int out_size, void* d_ws, size_t ws_size,
                              hipStream_t stream) {
    const float* x = (const float*)d_in[0];       // x
    const float* t = (const float*)d_in[1];       // target
    float* out = (float*)d_out;                   // scalar fp32 loss
    float* partial = (float*)d_ws;                // 10 * 2048 floats = 80 KB

    pow_sums_kernel<<<NBLK, 256, 0, stream>>>(x, t, partial);
    finalize_kernel<<<1, 256, 0, stream>>>(partial, out);
}

// Round 3
// 277.827 us; speedup vs baseline: 1.0202x; 1.0068x over previous
//
#include <hip/hip_runtime.h>

// Problem shape (fixed by reference setup_inputs):
//   x, target: [B=8, C=256, H=128, W=128] float32, contiguous.
//   Reduction over (B,H,W) -> per-channel moments 1..5; loss = sum of 5
//   RMSE-sum terms over the C=256 moment vectors.
#define B_DIM 8
#define C_DIM 256
#define HW    16384                 // 128*128 floats, contiguous per (b,c)
#define NSLAB (B_DIM * C_DIM)       // 2048 slabs per tensor
#define N_PER_CHAN (B_DIM * HW)     // 131072 elements per channel

// ---------------------------------------------------------------------------
// Kernel 1 (R3 variant): split-stream. Blocks [0,2048) read only x, blocks
// [2048,4096) read only target. Each block owns one contiguous 64 KB slab of
// ONE tensor -> pure unit-stride single-stream reads, 5 accumulators,
// ~26 VGPR -> guaranteed 8 waves/SIMD. This is the closest possible shape to
// the 3.15 TB/s/direction read microbench; if this doesn't beat 101 us, the
// ~2.65 TB/s per-direction fabric cap is the structural ceiling.
//
// Output layout (unchanged vs R2): partial[row * NSLAB + slab],
// rows 0..4 = x power sums 1..5, rows 5..9 = t power sums 1..5.
// ---------------------------------------------------------------------------
__global__ __launch_bounds__(256) void pow_sums_kernel(
    const float* __restrict__ x,
    const float* __restrict__ t,
    float* __restrict__ partial)
{
    const int bid  = blockIdx.x;
    const int tid  = threadIdx.x;
    const int slab = bid & (NSLAB - 1);
    const bool is_t = bid >= NSLAB;          // wave-uniform
    const float* __restrict__ src = is_t ? t : x;
    const int row0 = is_t ? 5 : 0;

    const float4* __restrict__ v = (const float4*)(src + (size_t)slab * HW);

    float s[5];
#pragma unroll
    for (int k = 0; k < 5; ++k) s[k] = 0.0f;

    // Powers 1..5 of one element accumulated into s[0..4].
#define ACC1(vv)                          \
    {                                     \
        float _v  = (vv);                 \
        float _v2 = _v * _v;              \
        float _v3 = _v2 * _v;             \
        s[0] += _v;                       \
        s[1] += _v2;                      \
        s[2] += _v3;                      \
        s[3] += _v2 * _v2;                \
        s[4] += _v3 * _v2;                \
    }
#define ACC4(f) ACC1((f).x) ACC1((f).y) ACC1((f).z) ACC1((f).w)

    // 16 float4/thread, consumed in 4 batches of 4 independent loads
    // (64 B/lane in flight per batch).
#pragma unroll
    for (int j = 0; j < 4; ++j) {
        const int base = tid + j * 1024;     // 4 * 256 threads
        float4 a0 = v[base];
        float4 a1 = v[base + 256];
        float4 a2 = v[base + 512];
        float4 a3 = v[base + 768];
        ACC4(a0) ACC4(a1) ACC4(a2) ACC4(a3)
    }
#undef ACC4
#undef ACC1

    // Wave-level butterfly reduce (wave = 64 lanes on gfx950).
#pragma unroll
    for (int off = 32; off > 0; off >>= 1) {
#pragma unroll
        for (int k = 0; k < 5; ++k) s[k] += __shfl_down(s[k], off, 64);
    }

    __shared__ float wsum[4][5];
    const int wave = tid >> 6;
    const int lane = tid & 63;
    if (lane == 0) {
#pragma unroll
        for (int k = 0; k < 5; ++k) wsum[wave][k] = s[k];
    }
    __syncthreads();

    if (tid < 5) {
        float vsum = wsum[0][tid] + wsum[1][tid] + wsum[2][tid] + wsum[3][tid];
        partial[(row0 + tid) * NSLAB + slab] = vsum;
    }
}

// ---------------------------------------------------------------------------
// Kernel 2: single block, 256 threads (thread c = channel c). Combines the
// 8 per-batch partials per channel in fp64, converts raw moments to central
// moments via binomial identities, reduces the 5 squared-diff sums across
// channels, writes the scalar loss.
// ---------------------------------------------------------------------------
__global__ __launch_bounds__(256) void finalize_kernel(
    const float* __restrict__ partial,
    float* __restrict__ out)
{
    const int c = threadIdx.x;  // channel

    double S[10];
#pragma unroll
    for (int k = 0; k < 10; ++k) S[k] = 0.0;

    for (int b = 0; b < B_DIM; ++b) {
        const int bid = b * C_DIM + c;  // coalesced across threads
#pragma unroll
        for (int k = 0; k < 10; ++k) S[k] += (double)partial[k * NSLAB + bid];
    }

    const double invN = 1.0 / (double)N_PER_CHAN;

    // x raw moments
    const double mux = S[0] * invN;
    const double M2x = S[1] * invN, M3x = S[2] * invN;
    const double M4x = S[3] * invN, M5x = S[4] * invN;
    // y raw moments
    const double muy = S[5] * invN;
    const double M2y = S[6] * invN, M3y = S[7] * invN;
    const double M4y = S[8] * invN, M5y = S[9] * invN;

    // Central moments via binomial expansion about the mean.
    const double mux2 = mux * mux, mux3 = mux2 * mux;
    const double c2x = M2x - mux2;
    const double c3x = M3x - 3.0 * mux * M2x + 2.0 * mux3;
    const double c4x = M4x - 4.0 * mux * M3x + 6.0 * mux2 * M2x - 3.0 * mux2 * mux2;
    const double c5x = M5x - 5.0 * mux * M4x + 10.0 * mux2 * M3x
                       - 10.0 * mux3 * M2x + 4.0 * mux3 * mux2;

    const double muy2 = muy * muy, muy3 = muy2 * muy;
    const double c2y = M2y - muy2;
    const double c3y = M3y - 3.0 * muy * M2y + 2.0 * muy3;
    const double c4y = M4y - 4.0 * muy * M3y + 6.0 * muy2 * M2y - 3.0 * muy2 * muy2;
    const double c5y = M5y - 5.0 * muy * M4y + 10.0 * muy2 * M3y
                       - 10.0 * muy3 * M2y + 4.0 * muy3 * muy2;

    const double d1 = mux - muy;
    const double d2 = c2x - c2y;
    const double d3 = c3x - c3y;
    const double d4 = c4x - c4y;
    const double d5 = c5x - c5y;

    __shared__ double red[5][C_DIM];
    red[0][c] = d1 * d1;
    red[1][c] = d2 * d2;
    red[2][c] = d3 * d3;
    red[3][c] = d4 * d4;
    red[4][c] = d5 * d5;
    __syncthreads();

    for (int st = 128; st > 0; st >>= 1) {
        if (c < st) {
#pragma unroll
            for (int k = 0; k < 5; ++k) red[k][c] += red[k][c + st];
        }
        __syncthreads();
    }

    if (c == 0) {
        out[0] = (float)(sqrt(red[0][0]) + sqrt(red[1][0]) + sqrt(red[2][0])
                         + sqrt(red[3][0]) + sqrt(red[4][0]));
    }
}

extern "C" void kernel_launch(void* const* d_in, const int* in_sizes, int n_in,
                              void* d_out, int out_size, void* d_ws, size_t ws_size,
                              hipStream_t stream) {
    const float* x = (const float*)d_in[0];       // x
    const float* t = (const float*)d_in[1];       // target
    float* out = (float*)d_out;                   // scalar fp32 loss
    float* partial = (float*)d_ws;                // 10 * 2048 floats = 80 KB

    pow_sums_kernel<<<2 * NSLAB, 256, 0, stream>>>(x, t, partial);
    finalize_kernel<<<1, 256, 0, stream>>>(partial, out);
}

// Round 5
// 252.021 us; speedup vs baseline: 1.1247x; 1.1024x over previous
//
#include <hip/hip_runtime.h>

// Problem shape (fixed by reference setup_inputs):
//   x, target: [B=8, C=256, H=128, W=128] float32, contiguous.
//   Reduction over (B,H,W) -> per-channel moments 1..5; loss = sum of 5
//   RMSE-sum terms over the C=256 moment vectors.
#define B_DIM 8
#define C_DIM 256
#define HW    16384                 // 128*128 floats, contiguous per (b,c)
#define NSLAB (B_DIM * C_DIM)       // 2048 slabs per tensor
#define N_PER_CHAN (B_DIM * HW)     // 131072 elements per channel

// Native clang vector for __builtin_nontemporal_load (HIP_vector_type is
// rejected by the builtin; ext_vector_type is accepted and still emits one
// global_load_dwordx4 with the nt bit set).
typedef float vfloat4 __attribute__((ext_vector_type(4)));

// ---------------------------------------------------------------------------
// Kernel 1 (R5 variant): nontemporal split-stream.
// R1-R3 post-mortem: delivered BW pinned at 2.65 TB/s across interleaved /
// deep-batched / split-stream shapes; CU-side resources all >=4x headroom
// (VALUBusy 12.7%, occupancy-insensitive). Limiter = memory-side miss path
// (~1.33 TB/s HBM fetch). This round: `nt` loads (no cache allocation on
// fills -> no victim/allocation overhead for stream data) + even/odd x/t
// block interleave so hot(L3)/cold(HBM) streams are concurrent from t=0.
//
// Output layout: partial[row * NSLAB + slab], rows 0..4 = x power sums 1..5,
// rows 5..9 = t power sums 1..5.
// ---------------------------------------------------------------------------
__global__ __launch_bounds__(256) void pow_sums_kernel(
    const float* __restrict__ x,
    const float* __restrict__ t,
    float* __restrict__ partial)
{
    const int bid  = blockIdx.x;
    const int tid  = threadIdx.x;
    const int slab = bid >> 1;               // even/odd interleave
    const bool is_t = (bid & 1) != 0;        // wave-uniform
    const float* __restrict__ src = is_t ? t : x;
    const int row0 = is_t ? 5 : 0;

    const vfloat4* __restrict__ v = (const vfloat4*)(src + (size_t)slab * HW);

    float s[5];
#pragma unroll
    for (int k = 0; k < 5; ++k) s[k] = 0.0f;

    // Powers 1..5 of one element accumulated into s[0..4].
#define ACC1(vv)                          \
    {                                     \
        float _v  = (vv);                 \
        float _v2 = _v * _v;              \
        float _v3 = _v2 * _v;             \
        s[0] += _v;                       \
        s[1] += _v2;                      \
        s[2] += _v3;                      \
        s[3] += _v2 * _v2;                \
        s[4] += _v3 * _v2;                \
    }
#define ACC4(f) ACC1((f).x) ACC1((f).y) ACC1((f).z) ACC1((f).w)

    // 16 float4/thread, consumed in 4 batches of 4 independent nt loads
    // (64 B/lane in flight per batch).
#pragma unroll
    for (int j = 0; j < 4; ++j) {
        const int base = tid + j * 1024;     // 4 * 256 threads
        vfloat4 a0 = __builtin_nontemporal_load(&v[base]);
        vfloat4 a1 = __builtin_nontemporal_load(&v[base + 256]);
        vfloat4 a2 = __builtin_nontemporal_load(&v[base + 512]);
        vfloat4 a3 = __builtin_nontemporal_load(&v[base + 768]);
        ACC4(a0) ACC4(a1) ACC4(a2) ACC4(a3)
    }
#undef ACC4
#undef ACC1

    // Wave-level butterfly reduce (wave = 64 lanes on gfx950).
#pragma unroll
    for (int off = 32; off > 0; off >>= 1) {
#pragma unroll
        for (int k = 0; k < 5; ++k) s[k] += __shfl_down(s[k], off, 64);
    }

    __shared__ float wsum[4][5];
    const int wave = tid >> 6;
    const int lane = tid & 63;
    if (lane == 0) {
#pragma unroll
        for (int k = 0; k < 5; ++k) wsum[wave][k] = s[k];
    }
    __syncthreads();

    if (tid < 5) {
        float vsum = wsum[0][tid] + wsum[1][tid] + wsum[2][tid] + wsum[3][tid];
        partial[(row0 + tid) * NSLAB + slab] = vsum;
    }
}

// ---------------------------------------------------------------------------
// Kernel 2: single block, 256 threads (thread c = channel c). Combines the
// 8 per-batch partials per channel in fp64, converts raw moments to central
// moments via binomial identities, reduces the 5 squared-diff sums across
// channels, writes the scalar loss.
// ---------------------------------------------------------------------------
__global__ __launch_bounds__(256) void finalize_kernel(
    const float* __restrict__ partial,
    float* __restrict__ out)
{
    const int c = threadIdx.x;  // channel

    double S[10];
#pragma unroll
    for (int k = 0; k < 10; ++k) S[k] = 0.0;

    for (int b = 0; b < B_DIM; ++b) {
        const int bid = b * C_DIM + c;  // coalesced across threads
#pragma unroll
        for (int k = 0; k < 10; ++k) S[k] += (double)partial[k * NSLAB + bid];
    }

    const double invN = 1.0 / (double)N_PER_CHAN;

    // x raw moments
    const double mux = S[0] * invN;
    const double M2x = S[1] * invN, M3x = S[2] * invN;
    const double M4x = S[3] * invN, M5x = S[4] * invN;
    // y raw moments
    const double muy = S[5] * invN;
    const double M2y = S[6] * invN, M3y = S[7] * invN;
    const double M4y = S[8] * invN, M5y = S[9] * invN;

    // Central moments via binomial expansion about the mean.
    const double mux2 = mux * mux, mux3 = mux2 * mux;
    const double c2x = M2x - mux2;
    const double c3x = M3x - 3.0 * mux * M2x + 2.0 * mux3;
    const double c4x = M4x - 4.0 * mux * M3x + 6.0 * mux2 * M2x - 3.0 * mux2 * mux2;
    const double c5x = M5x - 5.0 * mux * M4x + 10.0 * mux2 * M3x
                       - 10.0 * mux3 * M2x + 4.0 * mux3 * mux2;

    const double muy2 = muy * muy, muy3 = muy2 * muy;
    const double c2y = M2y - muy2;
    const double c3y = M3y - 3.0 * muy * M2y + 2.0 * muy3;
    const double c4y = M4y - 4.0 * muy * M3y + 6.0 * muy2 * M2y - 3.0 * muy2 * muy2;
    const double c5y = M5y - 5.0 * muy * M4y + 10.0 * muy2 * M3y
                       - 10.0 * muy3 * M2y + 4.0 * muy3 * muy2;

    const double d1 = mux - muy;
    const double d2 = c2x - c2y;
    const double d3 = c3x - c3y;
    const double d4 = c4x - c4y;
    const double d5 = c5x - c5y;

    __shared__ double red[5][C_DIM];
    red[0][c] = d1 * d1;
    red[1][c] = d2 * d2;
    red[2][c] = d3 * d3;
    red[3][c] = d4 * d4;
    red[4][c] = d5 * d5;
    __syncthreads();

    for (int st = 128; st > 0; st >>= 1) {
        if (c < st) {
#pragma unroll
            for (int k = 0; k < 5; ++k) red[k][c] += red[k][c + st];
        }
        __syncthreads();
    }

    if (c == 0) {
        out[0] = (float)(sqrt(red[0][0]) + sqrt(red[1][0]) + sqrt(red[2][0])
                         + sqrt(red[3][0]) + sqrt(red[4][0]));
    }
}

extern "C" void kernel_launch(void* const* d_in, const int* in_sizes, int n_in,
                              void* d_out, int out_size, void* d_ws, size_t ws_size,
                              hipStream_t stream) {
    const float* x = (const float*)d_in[0];       // x
    const float* t = (const float*)d_in[1];       // target
    float* out = (float*)d_out;                   // scalar fp32 loss
    float* partial = (float*)d_ws;                // 10 * 2048 floats = 80 KB

    pow_sums_kernel<<<2 * NSLAB, 256, 0, stream>>>(x, t, partial);
    finalize_kernel<<<1, 256, 0, stream>>>(partial, out);
}